// Round 15
// baseline (448.693 us; speedup 1.0000x reference)
//
#include <hip/hip_runtime.h>
#include <math.h>

#define B 2048
#define C 1024
#define NBLK 256   // sink persistent grid == CU count

typedef _Float16 v2h __attribute__((ext_vector_type(2)));

// ---------------------------------------------------------------------------
// Kernel 1: row softmax of y/2 -> fp16, with folded sentinel-fill + out=0.
// (byte-identical to round 13)
// ---------------------------------------------------------------------------
__global__ __launch_bounds__(256) void softmax_k(const float* __restrict__ ys,
                                                 const float* __restrict__ yt,
                                                 _Float16* __restrict__ ps,
                                                 _Float16* __restrict__ pt,
                                                 unsigned* __restrict__ sent,
                                                 float* __restrict__ out) {
    int b = blockIdx.x;
    int tid = threadIdx.x;

    unsigned gid = b * 256 + tid;
    if (gid < 40u * B) sent[gid] = 0xFFFFFFFFu;
    if (gid == 0) *out = 0.f;

    const float* in;
    _Float16* o;
    if (b < B) { in = ys + (size_t)b * C;        o = ps + (size_t)b * C; }
    else       { in = yt + (size_t)(b - B) * C;  o = pt + (size_t)(b - B) * C; }
    int lane = tid & 63, wave = tid >> 6;

    float4 v = reinterpret_cast<const float4*>(in)[tid];
    v.x *= 0.5f; v.y *= 0.5f; v.z *= 0.5f; v.w *= 0.5f;

    float mx = fmaxf(fmaxf(v.x, v.y), fmaxf(v.z, v.w));
    #pragma unroll
    for (int m = 32; m >= 1; m >>= 1) mx = fmaxf(mx, __shfl_xor(mx, m, 64));
    __shared__ float redm[4];
    if (lane == 0) redm[wave] = mx;
    __syncthreads();
    mx = fmaxf(fmaxf(redm[0], redm[1]), fmaxf(redm[2], redm[3]));

    float4 e;
    e.x = expf(v.x - mx); e.y = expf(v.y - mx);
    e.z = expf(v.z - mx); e.w = expf(v.w - mx);
    float s = e.x + e.y + e.z + e.w;
    #pragma unroll
    for (int m = 32; m >= 1; m >>= 1) s += __shfl_xor(s, m, 64);
    __shared__ float reds[4];
    if (lane == 0) reds[wave] = s;
    __syncthreads();
    s = reds[0] + reds[1] + reds[2] + reds[3];

    float inv = 1.0f / s;
    float2 st;
    v2h* sp = (v2h*)&st;
    sp[0] = (v2h){(_Float16)(e.x * inv), (_Float16)(e.y * inv)};
    sp[1] = (v2h){(_Float16)(e.z * inv), (_Float16)(e.w * inv)};
    reinterpret_cast<float2*>(o)[tid] = st;
}

// ---------------------------------------------------------------------------
// Kernel 2 (byte-identical to rounds 11/13 best config): 128x64 tiles,
// 2 independent blocks/CU, 512 thr, 4x4 frags, asm pk_min+pk_add, per-chunk
// dot2 fold, LDS double-buffer, fused Km+KmT normal-store epilogue.
// ---------------------------------------------------------------------------
__global__ __launch_bounds__(512)
__attribute__((amdgpu_waves_per_eu(4, 4)))
void cdist_k(const _Float16* __restrict__ ps,
             const _Float16* __restrict__ pt,
             float* __restrict__ Km,
             float* __restrict__ KmT) {
    __shared__ __align__(16) v2h As[2][16][132];
    __shared__ __align__(16) v2h Bs[2][16][68];
    int tid = threadIdx.x;
    int tx = tid & 15;          // [0,16): 4-col group
    int ty = tid >> 4;          // [0,32): 4-row group
    int r0 = blockIdx.y * 128, c0 = blockIdx.x * 64;

    float acc[4][4];
    v2h csum[4][4];
    #pragma unroll
    for (int i = 0; i < 4; ++i)
        #pragma unroll
        for (int j = 0; j < 4; ++j) {
            acc[i][j] = 0.f;
            csum[i][j] = (v2h){(_Float16)0.f, (_Float16)0.f};
        }

    int lr = tid >> 2;          // [0,128): A staging row
    int lq = tid & 3;           // float4 slot within the 32-elem chunk
    const float4* pa = reinterpret_cast<const float4*>(ps + (size_t)(r0 + lr) * C);
    const float4* pb = reinterpret_cast<const float4*>(
        pt + (size_t)(c0 + (lr & 63)) * C);
    const bool bload = (tid < 256);
    const v2h one2 = {(_Float16)1.0f, (_Float16)1.0f};

    // stage ch=0 into buf 0
    {
        float4 a0 = pa[lq];
        v2h* ah = (v2h*)&a0;
        #pragma unroll
        for (int c2 = 0; c2 < 4; ++c2)
            As[0][lq * 4 + c2][lr] = ah[c2];
        if (bload) {
            float4 b0 = pb[lq];
            v2h* bh = (v2h*)&b0;
            #pragma unroll
            for (int c2 = 0; c2 < 4; ++c2)
                Bs[0][lq * 4 + c2][lr] = bh[c2];
        }
    }
    __syncthreads();

    // prefetch ch=1 into registers
    float4 a1 = pa[4 + lq];
    float4 b1 = bload ? pb[4 + lq] : make_float4(0.f, 0.f, 0.f, 0.f);

    for (int ch = 0; ch < 32; ++ch) {
        int p = ch & 1;

        #pragma unroll
        for (int k2 = 0; k2 < 16; ++k2) {
            v2h a2[4], b2[4];
            *(float4*)&a2[0] = *(const float4*)&As[p][k2][ty * 4];
            *(float4*)&b2[0] = *(const float4*)&Bs[p][k2][tx * 4];
            #pragma unroll
            for (int i = 0; i < 4; ++i)
                #pragma unroll
                for (int j = 0; j < 4; ++j) {
                    v2h tmp;
                    asm("v_pk_min_f16 %1, %2, %3\n\t"
                        "v_pk_add_f16 %0, %0, %1"
                        : "+v"(csum[i][j]), "=&v"(tmp)
                        : "v"(a2[i]), "v"(b2[j]));
                }
        }
        // fold 16-term fp16 chunk sums into f32 accumulators (chain as before)
        #pragma unroll
        for (int i = 0; i < 4; ++i)
            #pragma unroll
            for (int j = 0; j < 4; ++j) {
                asm("v_dot2_f32_f16 %0, %1, %2, %0"
                    : "+v"(acc[i][j]) : "v"(csum[i][j]), "v"(one2));
                csum[i][j] = (v2h){(_Float16)0.f, (_Float16)0.f};
            }

        if (ch < 31) {
            int np = p ^ 1;
            v2h* ah = (v2h*)&a1;
            #pragma unroll
            for (int c2 = 0; c2 < 4; ++c2)
                As[np][lq * 4 + c2][lr] = ah[c2];
            if (bload) {
                v2h* bh = (v2h*)&b1;
                #pragma unroll
                for (int c2 = 0; c2 < 4; ++c2)
                    Bs[np][lq * 4 + c2][lr] = bh[c2];
            }
            __syncthreads();
            int nch = ch + 2;
            if (nch < 32) {              // prefetch lands under next compute
                a1 = pa[nch * 4 + lq];
                if (bload) b1 = pb[nch * 4 + lq];
            }
        }
    }

    // epilogue: e[i][j] = exp(20*S - 20), write Km rows and KmT columns
    float e[4][4];
    #pragma unroll
    for (int i = 0; i < 4; ++i)
        #pragma unroll
        for (int j = 0; j < 4; ++j)
            e[i][j] = __expf(20.f * acc[i][j] - 20.f);

    #pragma unroll
    for (int i = 0; i < 4; ++i) {
        int row = r0 + ty * 4 + i;
        float4 k0 = make_float4(e[i][0], e[i][1], e[i][2], e[i][3]);
        *reinterpret_cast<float4*>(&Km[(size_t)row * B + c0 + tx * 4]) = k0;
    }
    #pragma unroll
    for (int j = 0; j < 4; ++j) {
        int cj = c0 + tx * 4 + j;
        float4 v = make_float4(e[0][j], e[1][j], e[2][j], e[3][j]);
        *reinterpret_cast<float4*>(&KmT[(size_t)cj * B + r0 + ty * 4]) = v;
    }
}

// ---------------------------------------------------------------------------
// Relaxed agent-scope atomics: LLC-direct, no cache-maintenance ops
// (validated rounds 4-13 for small s/a traffic).
// ---------------------------------------------------------------------------
__device__ __forceinline__ void stf_rlx(float* p, float v) {
    __hip_atomic_store(p, v, __ATOMIC_RELAXED, __HIP_MEMORY_SCOPE_AGENT);
}
__device__ __forceinline__ float2 poll2(const float* p) {
    const unsigned long long* q = reinterpret_cast<const unsigned long long*>(p);
    unsigned long long v = __hip_atomic_load(q, __ATOMIC_RELAXED,
                                             __HIP_MEMORY_SCOPE_AGENT);
    while ((unsigned)v == 0xFFFFFFFFu || (unsigned)(v >> 32) == 0xFFFFFFFFu) {
        __builtin_amdgcn_s_sleep(1);
        v = __hip_atomic_load(q, __ATOMIC_RELAXED, __HIP_MEMORY_SCOPE_AGENT);
    }
    float2 r;
    r.x = __uint_as_float((unsigned)v);
    r.y = __uint_as_float((unsigned)(v >> 32));
    return r;
}
__device__ __forceinline__ float4 poll4(const float* p) {
    float2 lo = poll2(p);
    float2 hi = poll2(p + 2);
    return make_float4(lo.x, lo.y, hi.x, hi.y);
}

// ---------------------------------------------------------------------------
// Kernel 3 v12 (resubmission of round 14 -- infra failure, no counters; sync
// logic re-audited: barrier schedule has no read/write window overlap, the
// dependency graph is strictly monotonic -> no deadlock possible):
// sentinel dataflow as r13, but WAVE-0-ONLY POLLING with LDS broadcast.
// Theory: 131K threads spin-loading 128 LLC lines throttle the awaited
// stores; wave-0 polling drops per-word poll pressure ~32x. If this fails
// again the same way, the kernel is presumed guilty -> revert to r13.
// ---------------------------------------------------------------------------
__global__ __launch_bounds__(512)
__attribute__((amdgpu_waves_per_eu(2, 2)))
void sink_k(const float* __restrict__ Km,
            const float* __restrict__ KmT,
            float* __restrict__ sbuf,
            float* __restrict__ abuf,
            float* __restrict__ out) {
    __shared__ float part[2][8][8];
    __shared__ float a8[8];
    __shared__ float sv_lds[B];     // 8 KB: broadcast s_{t-1}
    __shared__ float av_lds[B];     // 8 KB: broadcast a_t
    int t0 = threadIdx.x;
    int lane = t0 & 63, wv = t0 >> 6;      // 8 waves
    int bid = blockIdx.x;
    int r0 = bid * 8;          // owned rows
    int c0 = bid * 8;          // owned cols
    int jx = 4 * t0;           // this thread's 4 columns (row phase)
    int rr = 4 * t0;           // this thread's 4 rows (col phase)

    // row block: K[r0+i][jx..jx+3]  (coalesced float4 per row)
    float4 kr[8];
    #pragma unroll
    for (int i = 0; i < 8; ++i)
        kr[i] = *reinterpret_cast<const float4*>(&Km[(size_t)(r0 + i) * B + jx]);

    // col block via KmT: kc[c][i] = K[rr+i][c0+c]  (coalesced float4 per col)
    float4 kc[8];
    #pragma unroll
    for (int c = 0; c < 8; ++c)
        kc[c] = *reinterpret_cast<const float4*>(&KmT[(size_t)(c0 + c) * B + rr]);

    for (int t = 1; t <= 20; ++t) {
        // ---- row phase: a = 1/(K * (1/s_{t-1})) ----
        float4 binv = make_float4(1.f, 1.f, 1.f, 1.f);
        if (t > 1) {
            // wave 0 polls + broadcasts s_{t-1} (32 words/lane)
            if (t0 < 64) {
                const float* src = &sbuf[(size_t)(t - 2) * B];
                #pragma unroll
                for (int g = 0; g < 8; ++g) {
                    int w = t0 * 32 + g * 4;
                    float4 v = poll4(&src[w]);
                    *reinterpret_cast<float4*>(&sv_lds[w]) = v;
                }
            }
            __syncthreads();
            float4 sv = *reinterpret_cast<const float4*>(&sv_lds[jx]);
            binv.x = 1.0f / sv.x; binv.y = 1.0f / sv.y;
            binv.z = 1.0f / sv.z; binv.w = 1.0f / sv.w;
        }
        #pragma unroll
        for (int i = 0; i < 8; ++i) {
            float v = kr[i].x * binv.x + kr[i].y * binv.y
                    + kr[i].z * binv.z + kr[i].w * binv.w;
            #pragma unroll
            for (int m = 32; m >= 1; m >>= 1) v += __shfl_xor(v, m, 64);
            if (lane == 0) part[0][i][wv] = v;
        }
        __syncthreads();
        float* a_t = abuf + (size_t)(t - 1) * B;
        if (t0 < 8) {
            float sum = 0.f;
            #pragma unroll
            for (int w = 0; w < 8; ++w) sum += part[0][t0][w];
            float av = 1.0f / sum;
            a8[t0] = av;
            stf_rlx(&a_t[r0 + t0], av);
        }

        // ---- col phase: s_t[c] = sum_i a_i K[i][c]  (owned columns) ----
        // wave 0 polls + broadcasts a_t
        if (t0 < 64) {
            #pragma unroll
            for (int g = 0; g < 8; ++g) {
                int w = t0 * 32 + g * 4;
                float4 v = poll4(&a_t[w]);
                *reinterpret_cast<float4*>(&av_lds[w]) = v;
            }
        }
        __syncthreads();
        float4 av4 = *reinterpret_cast<const float4*>(&av_lds[rr]);
        float p[8];
        #pragma unroll
        for (int c = 0; c < 8; ++c)
            p[c] = av4.x * kc[c].x + av4.y * kc[c].y
                 + av4.z * kc[c].z + av4.w * kc[c].w;
        #pragma unroll
        for (int c = 0; c < 8; ++c) {
            float v = p[c];
            #pragma unroll
            for (int m = 32; m >= 1; m >>= 1) v += __shfl_xor(v, m, 64);
            if (lane == 0) part[1][c][wv] = v;
        }
        __syncthreads();
        float* s_t = sbuf + (size_t)(t - 1) * B;
        if (t0 < 8) {
            float sum = 0.f;
            #pragma unroll
            for (int w = 0; w < 8; ++w) sum += part[1][t0][w];
            stf_rlx(&s_t[c0 + t0], sum);
        }
        // (no barrier: next phase's broadcast barrier protects part/sv/av)
    }

    // ---- fused loss: -1e-4 * sum_ij a_i K_ij (1/s20_j) ln K_ij ----
    float4 sv = poll4(&sbuf[(size_t)19 * B + jx]);
    float4 binv;
    binv.x = 1.0f / sv.x; binv.y = 1.0f / sv.y;
    binv.z = 1.0f / sv.z; binv.w = 1.0f / sv.w;
    float acc = 0.f;
    #pragma unroll
    for (int i = 0; i < 8; ++i) {
        float ai = a8[i];   // this block's own rows' a from iteration 20
        acc += ai * (kr[i].x * binv.x * __logf(kr[i].x) +
                     kr[i].y * binv.y * __logf(kr[i].y) +
                     kr[i].z * binv.z * __logf(kr[i].z) +
                     kr[i].w * binv.w * __logf(kr[i].w));
    }
    #pragma unroll
    for (int m = 32; m >= 1; m >>= 1) acc += __shfl_xor(acc, m, 64);
    if (lane == 0) part[0][0][wv] = acc;
    __syncthreads();
    if (t0 == 0) {
        float sum = 0.f;
        #pragma unroll
        for (int w = 0; w < 8; ++w) sum += part[0][0][w];
        atomicAdd(out, -0.1f * 0.001f * sum);
    }
}

// ---------------------------------------------------------------------------
extern "C" void kernel_launch(void* const* d_in, const int* in_sizes, int n_in,
                              void* d_out, int out_size, void* d_ws, size_t ws_size,
                              hipStream_t stream) {
    const float* ys = (const float*)d_in[0];
    const float* yt = (const float*)d_in[1];
    float* out = (float*)d_out;

    char* wsb = (char*)d_ws;
    _Float16* ps = (_Float16*)wsb;                               // 4 MB
    _Float16* pt = (_Float16*)(wsb + (size_t)B * C * 2);         // 4 MB
    float* Km    = (float*)(wsb + (size_t)2 * B * C * 2);        // 16.8 MB
    float* KmT   = Km + (size_t)B * B;                           // 16.8 MB
    float* sbuf  = KmT + (size_t)B * B;                          // 20*B floats
    float* abuf  = sbuf + (size_t)20 * B;                        // 20*B floats

    softmax_k<<<2 * B, 256, 0, stream>>>(ys, yt, ps, pt,
                                         (unsigned*)sbuf, out);
    cdist_k<<<dim3(32, 16), 512, 0, stream>>>(ps, pt, Km, KmT);
    sink_k<<<NBLK, 512, 0, stream>>>(Km, KmT, sbuf, abuf, out);
}

// Round 16
// 356.883 us; speedup vs baseline: 1.2573x; 1.2573x over previous
//
#include <hip/hip_runtime.h>
#include <math.h>

#define B 2048
#define C 1024
#define NBLK 256   // sink persistent grid == CU count

typedef _Float16 v2h __attribute__((ext_vector_type(2)));

// ---------------------------------------------------------------------------
// Kernel 1: row softmax of y/2 -> fp16, with folded sentinel-fill + out=0.
// (byte-identical to round 13, the best-measured configuration: 357.2 us)
// ---------------------------------------------------------------------------
__global__ __launch_bounds__(256) void softmax_k(const float* __restrict__ ys,
                                                 const float* __restrict__ yt,
                                                 _Float16* __restrict__ ps,
                                                 _Float16* __restrict__ pt,
                                                 unsigned* __restrict__ sent,
                                                 float* __restrict__ out) {
    int b = blockIdx.x;
    int tid = threadIdx.x;

    unsigned gid = b * 256 + tid;
    if (gid < 40u * B) sent[gid] = 0xFFFFFFFFu;
    if (gid == 0) *out = 0.f;

    const float* in;
    _Float16* o;
    if (b < B) { in = ys + (size_t)b * C;        o = ps + (size_t)b * C; }
    else       { in = yt + (size_t)(b - B) * C;  o = pt + (size_t)(b - B) * C; }
    int lane = tid & 63, wave = tid >> 6;

    float4 v = reinterpret_cast<const float4*>(in)[tid];
    v.x *= 0.5f; v.y *= 0.5f; v.z *= 0.5f; v.w *= 0.5f;

    float mx = fmaxf(fmaxf(v.x, v.y), fmaxf(v.z, v.w));
    #pragma unroll
    for (int m = 32; m >= 1; m >>= 1) mx = fmaxf(mx, __shfl_xor(mx, m, 64));
    __shared__ float redm[4];
    if (lane == 0) redm[wave] = mx;
    __syncthreads();
    mx = fmaxf(fmaxf(redm[0], redm[1]), fmaxf(redm[2], redm[3]));

    float4 e;
    e.x = expf(v.x - mx); e.y = expf(v.y - mx);
    e.z = expf(v.z - mx); e.w = expf(v.w - mx);
    float s = e.x + e.y + e.z + e.w;
    #pragma unroll
    for (int m = 32; m >= 1; m >>= 1) s += __shfl_xor(s, m, 64);
    __shared__ float reds[4];
    if (lane == 0) reds[wave] = s;
    __syncthreads();
    s = reds[0] + reds[1] + reds[2] + reds[3];

    float inv = 1.0f / s;
    float2 st;
    v2h* sp = (v2h*)&st;
    sp[0] = (v2h){(_Float16)(e.x * inv), (_Float16)(e.y * inv)};
    sp[1] = (v2h){(_Float16)(e.z * inv), (_Float16)(e.w * inv)};
    reinterpret_cast<float2*>(o)[tid] = st;
}

// ---------------------------------------------------------------------------
// Kernel 2 (byte-identical to rounds 11/13 best config): 128x64 tiles,
// 2 independent blocks/CU (grid 32x16), 512 thr, 4x4 frags, asm
// pk_min+pk_add inner pair, per-chunk dot2 fold, LDS double-buffer, fused
// Km+KmT normal-store epilogue. Measured at 91% of the packed-f16 VALU
// issue floor (VOP3P = 4 cyc/wave-op on gfx950).
// ---------------------------------------------------------------------------
__global__ __launch_bounds__(512)
__attribute__((amdgpu_waves_per_eu(4, 4)))
void cdist_k(const _Float16* __restrict__ ps,
             const _Float16* __restrict__ pt,
             float* __restrict__ Km,
             float* __restrict__ KmT) {
    __shared__ __align__(16) v2h As[2][16][132];
    __shared__ __align__(16) v2h Bs[2][16][68];
    int tid = threadIdx.x;
    int tx = tid & 15;          // [0,16): 4-col group
    int ty = tid >> 4;          // [0,32): 4-row group
    int r0 = blockIdx.y * 128, c0 = blockIdx.x * 64;

    float acc[4][4];
    v2h csum[4][4];
    #pragma unroll
    for (int i = 0; i < 4; ++i)
        #pragma unroll
        for (int j = 0; j < 4; ++j) {
            acc[i][j] = 0.f;
            csum[i][j] = (v2h){(_Float16)0.f, (_Float16)0.f};
        }

    int lr = tid >> 2;          // [0,128): A staging row
    int lq = tid & 3;           // float4 slot within the 32-elem chunk
    const float4* pa = reinterpret_cast<const float4*>(ps + (size_t)(r0 + lr) * C);
    const float4* pb = reinterpret_cast<const float4*>(
        pt + (size_t)(c0 + (lr & 63)) * C);
    const bool bload = (tid < 256);
    const v2h one2 = {(_Float16)1.0f, (_Float16)1.0f};

    // stage ch=0 into buf 0
    {
        float4 a0 = pa[lq];
        v2h* ah = (v2h*)&a0;
        #pragma unroll
        for (int c2 = 0; c2 < 4; ++c2)
            As[0][lq * 4 + c2][lr] = ah[c2];
        if (bload) {
            float4 b0 = pb[lq];
            v2h* bh = (v2h*)&b0;
            #pragma unroll
            for (int c2 = 0; c2 < 4; ++c2)
                Bs[0][lq * 4 + c2][lr] = bh[c2];
        }
    }
    __syncthreads();

    // prefetch ch=1 into registers
    float4 a1 = pa[4 + lq];
    float4 b1 = bload ? pb[4 + lq] : make_float4(0.f, 0.f, 0.f, 0.f);

    for (int ch = 0; ch < 32; ++ch) {
        int p = ch & 1;

        #pragma unroll
        for (int k2 = 0; k2 < 16; ++k2) {
            v2h a2[4], b2[4];
            *(float4*)&a2[0] = *(const float4*)&As[p][k2][ty * 4];
            *(float4*)&b2[0] = *(const float4*)&Bs[p][k2][tx * 4];
            #pragma unroll
            for (int i = 0; i < 4; ++i)
                #pragma unroll
                for (int j = 0; j < 4; ++j) {
                    v2h tmp;
                    asm("v_pk_min_f16 %1, %2, %3\n\t"
                        "v_pk_add_f16 %0, %0, %1"
                        : "+v"(csum[i][j]), "=&v"(tmp)
                        : "v"(a2[i]), "v"(b2[j]));
                }
        }
        // fold 16-term fp16 chunk sums into f32 accumulators (chain as before)
        #pragma unroll
        for (int i = 0; i < 4; ++i)
            #pragma unroll
            for (int j = 0; j < 4; ++j) {
                asm("v_dot2_f32_f16 %0, %1, %2, %0"
                    : "+v"(acc[i][j]) : "v"(csum[i][j]), "v"(one2));
                csum[i][j] = (v2h){(_Float16)0.f, (_Float16)0.f};
            }

        if (ch < 31) {
            int np = p ^ 1;
            v2h* ah = (v2h*)&a1;
            #pragma unroll
            for (int c2 = 0; c2 < 4; ++c2)
                As[np][lq * 4 + c2][lr] = ah[c2];
            if (bload) {
                v2h* bh = (v2h*)&b1;
                #pragma unroll
                for (int c2 = 0; c2 < 4; ++c2)
                    Bs[np][lq * 4 + c2][lr] = bh[c2];
            }
            __syncthreads();
            int nch = ch + 2;
            if (nch < 32) {              // prefetch lands under next compute
                a1 = pa[nch * 4 + lq];
                if (bload) b1 = pb[nch * 4 + lq];
            }
        }
    }

    // epilogue: e[i][j] = exp(20*S - 20), write Km rows and KmT columns
    float e[4][4];
    #pragma unroll
    for (int i = 0; i < 4; ++i)
        #pragma unroll
        for (int j = 0; j < 4; ++j)
            e[i][j] = __expf(20.f * acc[i][j] - 20.f);

    #pragma unroll
    for (int i = 0; i < 4; ++i) {
        int row = r0 + ty * 4 + i;
        float4 k0 = make_float4(e[i][0], e[i][1], e[i][2], e[i][3]);
        *reinterpret_cast<float4*>(&Km[(size_t)row * B + c0 + tx * 4]) = k0;
    }
    #pragma unroll
    for (int j = 0; j < 4; ++j) {
        int cj = c0 + tx * 4 + j;
        float4 v = make_float4(e[0][j], e[1][j], e[2][j], e[3][j]);
        *reinterpret_cast<float4*>(&KmT[(size_t)cj * B + r0 + ty * 4]) = v;
    }
}

// ---------------------------------------------------------------------------
// Relaxed agent-scope atomics: LLC-direct, no cache-maintenance ops
// (validated rounds 4-15 for small s/a traffic).
// ---------------------------------------------------------------------------
__device__ __forceinline__ void stf_rlx(float* p, float v) {
    __hip_atomic_store(p, v, __ATOMIC_RELAXED, __HIP_MEMORY_SCOPE_AGENT);
}
__device__ __forceinline__ float2 poll2(const float* p) {
    const unsigned long long* q = reinterpret_cast<const unsigned long long*>(p);
    unsigned long long v = __hip_atomic_load(q, __ATOMIC_RELAXED,
                                             __HIP_MEMORY_SCOPE_AGENT);
    while ((unsigned)v == 0xFFFFFFFFu || (unsigned)(v >> 32) == 0xFFFFFFFFu) {
        __builtin_amdgcn_s_sleep(1);
        v = __hip_atomic_load(q, __ATOMIC_RELAXED, __HIP_MEMORY_SCOPE_AGENT);
    }
    float2 r;
    r.x = __uint_as_float((unsigned)v);
    r.y = __uint_as_float((unsigned)(v >> 32));
    return r;
}
__device__ __forceinline__ float4 poll4(const float* p) {
    float2 lo = poll2(p);
    float2 hi = poll2(p + 2);
    return make_float4(lo.x, lo.y, hi.x, hi.y);
}

// ---------------------------------------------------------------------------
// Kernel 3 (byte-identical to round 13): persistent Sinkhorn + loss,
// ALL-THREAD sentinel dataflow sync — the measured optimum of five designs
// (acq/rel gridbar 83 us/phase, relaxed gridbar 5.8, epoch-flag 5.8, wave-0
// broadcast 6.3 [r15: serialized 16 dependent LLC trips/lane], all-thread
// sentinel 4.0-4.6). Per-phase floor = LLC propagation + 256-block skew on
// a 40-deep serial all-to-all chain.
// ---------------------------------------------------------------------------
__global__ __launch_bounds__(512)
__attribute__((amdgpu_waves_per_eu(2, 2)))
void sink_k(const float* __restrict__ Km,
            const float* __restrict__ KmT,
            float* __restrict__ sbuf,
            float* __restrict__ abuf,
            float* __restrict__ out) {
    __shared__ float part[2][8][8];
    __shared__ float a8[8];
    int t0 = threadIdx.x;
    int lane = t0 & 63, wv = t0 >> 6;      // 8 waves
    int bid = blockIdx.x;
    int r0 = bid * 8;          // owned rows
    int c0 = bid * 8;          // owned cols
    int jx = 4 * t0;           // this thread's 4 columns (row phase)
    int rr = 4 * t0;           // this thread's 4 rows (col phase)

    // row block: K[r0+i][jx..jx+3]  (coalesced float4 per row)
    float4 kr[8];
    #pragma unroll
    for (int i = 0; i < 8; ++i)
        kr[i] = *reinterpret_cast<const float4*>(&Km[(size_t)(r0 + i) * B + jx]);

    // col block via KmT: kc[c][i] = K[rr+i][c0+c]  (coalesced float4 per col)
    float4 kc[8];
    #pragma unroll
    for (int c = 0; c < 8; ++c)
        kc[c] = *reinterpret_cast<const float4*>(&KmT[(size_t)(c0 + c) * B + rr]);

    for (int t = 1; t <= 20; ++t) {
        // ---- row phase: a = 1/(K * (1/s_{t-1})) ----
        float4 binv = make_float4(1.f, 1.f, 1.f, 1.f);
        if (t > 1) {
            float4 sv = poll4(&sbuf[(size_t)(t - 2) * B + jx]);
            binv.x = 1.0f / sv.x; binv.y = 1.0f / sv.y;
            binv.z = 1.0f / sv.z; binv.w = 1.0f / sv.w;
        }
        #pragma unroll
        for (int i = 0; i < 8; ++i) {
            float v = kr[i].x * binv.x + kr[i].y * binv.y
                    + kr[i].z * binv.z + kr[i].w * binv.w;
            #pragma unroll
            for (int m = 32; m >= 1; m >>= 1) v += __shfl_xor(v, m, 64);
            if (lane == 0) part[0][i][wv] = v;
        }
        __syncthreads();
        float* a_t = abuf + (size_t)(t - 1) * B;
        if (t0 < 8) {
            float sum = 0.f;
            #pragma unroll
            for (int w = 0; w < 8; ++w) sum += part[0][t0][w];
            float av = 1.0f / sum;
            a8[t0] = av;
            stf_rlx(&a_t[r0 + t0], av);
        }
        // (no barrier: part[0] next written after the col-phase sync)

        // ---- col phase: s_t[c] = sum_i a_i K[i][c]  (owned columns) ----
        float4 av4 = poll4(&a_t[rr]);   // a for this thread's 4 rows
        float p[8];
        #pragma unroll
        for (int c = 0; c < 8; ++c)
            p[c] = av4.x * kc[c].x + av4.y * kc[c].y
                 + av4.z * kc[c].z + av4.w * kc[c].w;
        #pragma unroll
        for (int c = 0; c < 8; ++c) {
            float v = p[c];
            #pragma unroll
            for (int m = 32; m >= 1; m >>= 1) v += __shfl_xor(v, m, 64);
            if (lane == 0) part[1][c][wv] = v;
        }
        __syncthreads();
        float* s_t = sbuf + (size_t)(t - 1) * B;
        if (t0 < 8) {
            float sum = 0.f;
            #pragma unroll
            for (int w = 0; w < 8; ++w) sum += part[1][t0][w];
            stf_rlx(&s_t[c0 + t0], sum);
        }
        // (no barrier: parity buffers protect part[1] until next sync)
    }

    // ---- fused loss: -1e-4 * sum_ij a_i K_ij (1/s20_j) ln K_ij ----
    float4 sv = poll4(&sbuf[(size_t)19 * B + jx]);
    float4 binv;
    binv.x = 1.0f / sv.x; binv.y = 1.0f / sv.y;
    binv.z = 1.0f / sv.z; binv.w = 1.0f / sv.w;
    float acc = 0.f;
    #pragma unroll
    for (int i = 0; i < 8; ++i) {
        float ai = a8[i];   // this block's own rows' a from iteration 20
        acc += ai * (kr[i].x * binv.x * __logf(kr[i].x) +
                     kr[i].y * binv.y * __logf(kr[i].y) +
                     kr[i].z * binv.z * __logf(kr[i].z) +
                     kr[i].w * binv.w * __logf(kr[i].w));
    }
    #pragma unroll
    for (int m = 32; m >= 1; m >>= 1) acc += __shfl_xor(acc, m, 64);
    if (lane == 0) part[0][0][wv] = acc;
    __syncthreads();
    if (t0 == 0) {
        float sum = 0.f;
        #pragma unroll
        for (int w = 0; w < 8; ++w) sum += part[0][0][w];
        atomicAdd(out, -0.1f * 0.001f * sum);
    }
}

// ---------------------------------------------------------------------------
extern "C" void kernel_launch(void* const* d_in, const int* in_sizes, int n_in,
                              void* d_out, int out_size, void* d_ws, size_t ws_size,
                              hipStream_t stream) {
    const float* ys = (const float*)d_in[0];
    const float* yt = (const float*)d_in[1];
    float* out = (float*)d_out;

    char* wsb = (char*)d_ws;
    _Float16* ps = (_Float16*)wsb;                               // 4 MB
    _Float16* pt = (_Float16*)(wsb + (size_t)B * C * 2);         // 4 MB
    float* Km    = (float*)(wsb + (size_t)2 * B * C * 2);        // 16.8 MB
    float* KmT   = Km + (size_t)B * B;                           // 16.8 MB
    float* sbuf  = KmT + (size_t)B * B;                          // 20*B floats
    float* abuf  = sbuf + (size_t)20 * B;                        // 20*B floats

    // sentinel fill + out zero are folded into softmax_k (saves two fill
    // dispatches and their stream drains).
    softmax_k<<<2 * B, 256, 0, stream>>>(ys, yt, ps, pt,
                                         (unsigned*)sbuf, out);
    cdist_k<<<dim3(32, 16), 512, 0, stream>>>(ps, pt, Km, KmT);
    sink_k<<<NBLK, 512, 0, stream>>>(Km, KmT, sbuf, abuf, out);
}